// Round 1
// baseline (190.438 us; speedup 1.0000x reference)
//
#include <hip/hip_runtime.h>
#include <hip/hip_bf16.h>
#include <cstdint>
#include <cstddef>

// Problem constants (fixed shapes per reference)
#define NROWS 8192
#define DIM   1024
#define BMR 256           // block rows
#define BNC 128           // block cols
#define BK  32            // K depth per pipeline stage; 32 stages
#define NKS (DIM / BK)
#define NBLK 1056         // sum_{a<32}(2a+2) tiles = 8 XCDs x 132
#define EPS 1e-8f
// E pre-scaled by sqrt(10*log2(e)) so MFMA accumulates 10*log2(e)*<a,b>;
// epilogue is a bare exp2f.
#define PRESCALE 3.798288f

// LDS geometry: 3 buffers x (A 256x32 + B 128x32) bf16 = 3 x 24 KB = 72 KB
#define ABUF 8192         // elems per A tile
#define BUFE 12288        // elems per buffer (A ++ B)

typedef short  bf16x8  __attribute__((ext_vector_type(8)));
typedef float  floatx4 __attribute__((ext_vector_type(4)));

typedef __attribute__((address_space(1))) const void CGV;
typedef __attribute__((address_space(3))) void LV;

__device__ __forceinline__ void async_load16(const void* g, void* l) {
    __builtin_amdgcn_global_load_lds((CGV*)g, (LV*)l, 16, 0, 0);
}

__device__ __forceinline__ unsigned short f2bf_rne(float f) {
    union { float f; unsigned u; } c; c.f = f;
    unsigned u = c.u;
    unsigned r = (u + 0x7fffu + ((u >> 16) & 1u)) >> 16;
    return (unsigned short)r;
}

// ---------------------------------------------------------------------------
// Kernel A: fp32 -> bf16 (RNE) with PRESCALE folded in. First 64 blocks also
// zero the 16384-float accumulator region.
// ---------------------------------------------------------------------------
__global__ __launch_bounds__(256) void convert_kernel(
    const float* __restrict__ in, unsigned short* __restrict__ out,
    float* __restrict__ accum /* all_sum ++ pos_sum, 2*NROWS floats */)
{
    int i = (blockIdx.x * 256 + threadIdx.x) * 4;
    float4 v = *(const float4*)(in + i);
    ushort4 o;
    o.x = f2bf_rne(v.x * PRESCALE);
    o.y = f2bf_rne(v.y * PRESCALE);
    o.z = f2bf_rne(v.z * PRESCALE);
    o.w = f2bf_rne(v.w * PRESCALE);
    *(ushort4*)(out + i) = o;
    if (blockIdx.x < (2 * NROWS) / 256)
        accum[blockIdx.x * 256 + threadIdx.x] = 0.0f;
}

// ---------------------------------------------------------------------------
// Kernel B: symmetric-half fused GEMM, triple-buffered counted-vmcnt pipeline.
// Evidence R12 (this round's theory): every pipe <=27%, L3-warm replay same
// speed -> phase-serialization, not BW. The dbuf+__syncthreads structure
// forces a vmcnt(0) drain at every barrier (the documented ~900TF ceiling);
// counted vmcnt (T4) requires loads that legally stay in flight ACROSS the
// barrier, which dbuf cannot provide. Triple buffer can:
//   iter t: compute buf[t%3] (complete), tile t+1 in flight, stage t+2 into
//   buf[(t+2)%3] (last read at iter t-1, reads retired by data-dep lgkmcnt
//   before that iteration's barrier). s_waitcnt vmcnt(3) retires tile t+1;
//   tile t+2's 3 loads/thread stay in flight across s_barrier.
// 256x128 tiles (85 FLOP/staged-byte), 512 thr = 8 waves of 64x64, LDS 72 KB
// -> 2 blocks/CU (4 waves/SIMD) for cross-block MFMA/barrier overlap + T5
// setprio arbitrage. 1056 tiles = 8x132 XCD-local for A-panel L2 reuse.
// UNIFORM symmetry (R11-verified): keep strictly-lower (grow > gcol); each
// element feeds row grow AND col gcol — every unordered pair exactly once.
// Swizzle (R3/R9/R11-verified scheme, re-parameterized for 4 chunks/row):
// LDS[row][s] holds global chunk s ^ (row&3); read slot quad ^ (colw&3).
// global_load_lds dest stays linear (m104); swizzle applied on the GLOBAL
// source address (m173 pattern). K-accumulation order identical to the
// BK=64 version (two MFMAs/acc/64-K there == two 32-K stages here).
// ---------------------------------------------------------------------------
__global__ __launch_bounds__(512, 4) void gemm_fused_kernel(
    const unsigned short* __restrict__ E,   // bf16 bits (prescaled), [NROWS][DIM]
    const int*            __restrict__ labels,
    float*                __restrict__ all_sum,
    float*                __restrict__ pos_sum)
{
    __shared__ __align__(16) unsigned short S[3 * BUFE];   // 72 KB

    const int tid  = threadIdx.x;
    const int lane = tid & 63;
    const int w    = tid >> 6;      // wave 0..7
    const int wm   = w >> 1;        // row band wm*64 within tile
    const int wn   = w & 1;         // col band wn*64
    const int colw = lane & 15;
    const int quad = lane >> 4;

    // XCD-local linear tile id, then triangle decode over 256x128 tiles:
    // tile (a,c) with c <= 2a+1; t = a*(a+1) + c.
    const int b = blockIdx.x;
    const int t = (b & 7) * 132 + (b >> 3);     // 1056 = 8 x 132
    int a = (int)((sqrtf(4.0f * (float)t + 1.0f) - 1.0f) * 0.5f);
    while ((a + 1) * (a + 2) <= t) ++a;
    while (a * (a + 1) > t) --a;
    const int c = t - a * (a + 1);

    const int rBase = a * BMR;      // rows (A tile)
    const int cBase = c * BNC;      // cols (B tile)

    // Staging: A tile 256x32 = 1024 chunks of 16B, B tile 512 chunks; 512
    // threads x (2 A + 1 B). Wave w instr j writes LDS chunks w*128+j*64+lane
    // (A) / w*64+lane (B) linearly; the matching global chunk for LDS slot
    // s of row r is s ^ (r&3), i.e. gch = (lane&3) ^ ((lane>>2)&3).
    const int l4  = lane >> 2;                  // row within 16-row group
    const int gch = (lane & 3) ^ (l4 & 3);      // pre-swizzled global chunk
    const unsigned short* gA0 = E + (size_t)(rBase + w * 32 + l4) * DIM + gch * 8;
    const unsigned short* gA1 = gA0 + (size_t)16 * DIM;
    const unsigned short* gB  = E + (size_t)(cBase + w * 16 + l4) * DIM + gch * 8;
    const int aL0 = (w * 128 + lane) * 8;       // A lds elem base, j=0 (+512 for j=1)
    const int bL  = (w * 64 + lane) * 8;        // B lds elem base

    // Fragment reads: row = band + mt/nt*16 + colw; slot = quad ^ (colw&3).
    const int fs    = (quad ^ (colw & 3)) * 8;
    const int aBase = (wm * 64 + colw) * BK + fs;
    const int bBase = (wn * 64 + colw) * BK + fs;

    floatx4 acc[4][4];
    #pragma unroll
    for (int i = 0; i < 4; ++i)
        #pragma unroll
        for (int j = 0; j < 4; ++j)
            acc[i][j] = (floatx4)0.0f;

#define STAGE(T, SB) do { \
        async_load16(gA0 + (T) * BK, &S[(SB) * BUFE + aL0]);        \
        async_load16(gA1 + (T) * BK, &S[(SB) * BUFE + aL0 + 512]);  \
        async_load16(gB  + (T) * BK, &S[(SB) * BUFE + ABUF + bL]);  \
    } while (0)

    // Prologue: tiles 0 and 1 in flight; retire tile 0 (oldest 3), keep
    // tile 1's 3 loads in flight across the barrier.
    STAGE(0, 0);
    STAGE(1, 1);
    asm volatile("s_waitcnt vmcnt(3)" ::: "memory");
    __builtin_amdgcn_s_barrier();
    __builtin_amdgcn_sched_barrier(0);

    #pragma unroll
    for (int kt = 0; kt < NKS; ++kt) {
        const int rb = kt % 3;          // read buffer (compile-time)
        const int sb = (kt + 2) % 3;    // stage buffer

        bf16x8 bF[4];
        #pragma unroll
        for (int nt = 0; nt < 4; ++nt)
            bF[nt] = *(const bf16x8*)&S[rb * BUFE + ABUF + bBase + nt * 16 * BK];

        if (kt < NKS - 2) STAGE(kt + 2, sb);

        __builtin_amdgcn_s_setprio(1);
        #pragma unroll
        for (int mt = 0; mt < 4; ++mt) {
            bf16x8 aF = *(const bf16x8*)&S[rb * BUFE + aBase + mt * 16 * BK];
            #pragma unroll
            for (int nt = 0; nt < 4; ++nt)
                acc[mt][nt] = __builtin_amdgcn_mfma_f32_16x16x32_bf16(
                    aF, bF[nt], acc[mt][nt], 0, 0, 0);
        }
        __builtin_amdgcn_s_setprio(0);

        // Pin the boundary: no MFMA/ds_read may migrate across (rule 18),
        // then retire tile kt+1's loads (counted — kt+2's stay in flight).
        __builtin_amdgcn_sched_barrier(0);
        if (kt < NKS - 2)
            asm volatile("s_waitcnt vmcnt(3) lgkmcnt(0)" ::: "memory");
        else
            asm volatile("s_waitcnt vmcnt(0) lgkmcnt(0)" ::: "memory");
        __builtin_amdgcn_s_barrier();
        __builtin_amdgcn_sched_barrier(0);
    }
#undef STAGE

    // Epilogue. C/D layout (16x16x32): col = lane&15, row = quad*4 + reg.
    // Uniform rule: element (grow, gcol) counts iff grow > gcol; contributes
    // to row grow AND col gcol (R11-verified).
    float labc[4];
    int   gcolv[4];
    #pragma unroll
    for (int nt = 0; nt < 4; ++nt) {
        gcolv[nt] = cBase + wn * 64 + nt * 16 + colw;
        labc[nt]  = (float)labels[gcolv[nt]];
    }

    float colAll[4] = {0.f, 0.f, 0.f, 0.f};
    float colPos[4] = {0.f, 0.f, 0.f, 0.f};

    #pragma unroll
    for (int mt = 0; mt < 4; ++mt) {
        const int growBase = rBase + wm * 64 + mt * 16 + quad * 4;
        #pragma unroll
        for (int r = 0; r < 4; ++r) {
            const int grow = growBase + r;
            const float labr = (float)labels[grow];
            float sAll = 0.f, sPos = 0.f;
            #pragma unroll
            for (int nt = 0; nt < 4; ++nt) {
                float ev = exp2f(acc[mt][nt][r]);   // PRESCALE folded into E
                ev = (grow > gcolv[nt]) ? ev : 0.0f; // strictly-lower only
                sAll += ev;
                sPos += ev * labc[nt];
                colAll[nt] += ev;
                colPos[nt] += ev * labr;
            }
            // row-reduce across the 16 lanes (same quad) sharing this row
            #pragma unroll
            for (int off = 1; off < 16; off <<= 1) {
                sAll += __shfl_xor(sAll, off);
                sPos += __shfl_xor(sPos, off);
            }
            if (colw == 0 && sAll != 0.f) {
                atomicAdd(&all_sum[grow], sAll);
                atomicAdd(&pos_sum[grow], sPos);
            }
        }
    }

    // col-reduce: sum across quads (lanes differing in bits 4,5)
    #pragma unroll
    for (int nt = 0; nt < 4; ++nt) {
        float aa = colAll[nt], p = colPos[nt];
        aa += __shfl_xor(aa, 16);  p += __shfl_xor(p, 16);
        aa += __shfl_xor(aa, 32);  p += __shfl_xor(p, 32);
        if (quad == 0 && aa != 0.f) {
            atomicAdd(&all_sum[gcolv[nt]], aa);
            atomicAdd(&pos_sum[gcolv[nt]], p);
        }
    }
}

// ---------------------------------------------------------------------------
// Kernel C: loss = mean over rows with lab==1 of -log(pos/(all+eps)); 0 if n_ref<2
// ---------------------------------------------------------------------------
__global__ __launch_bounds__(1024) void finalize_kernel(
    const float* __restrict__ all_sum,
    const float* __restrict__ pos_sum,
    const int*   __restrict__ labels,
    float*       __restrict__ out)
{
    __shared__ float sSum[1024];
    __shared__ float sCnt[1024];
    const int tid = threadIdx.x;
    float lsum = 0.f, lcnt = 0.f;
    for (int i = tid; i < NROWS; i += 1024) {
        if (labels[i] > 0) {
            float p = pos_sum[i];
            float a = all_sum[i] + EPS;
            lsum += -logf(p / a);
            lcnt += 1.0f;
        }
    }
    sSum[tid] = lsum;
    sCnt[tid] = lcnt;
    __syncthreads();
    for (int s = 512; s > 0; s >>= 1) {
        if (tid < s) { sSum[tid] += sSum[tid + s]; sCnt[tid] += sCnt[tid + s]; }
        __syncthreads();
    }
    if (tid == 0) {
        float n = sCnt[0];
        out[0] = (n < 2.0f) ? 0.0f : sSum[0] / fmaxf(n, 1.0f);
    }
}

// ---------------------------------------------------------------------------
extern "C" void kernel_launch(void* const* d_in, const int* in_sizes, int n_in,
                              void* d_out, int out_size, void* d_ws, size_t ws_size,
                              hipStream_t stream) {
    const float* emb    = (const float*)d_in[0];
    const int*   labels = (const int*)d_in[1];
    float*       out    = (float*)d_out;

    // workspace layout: [bf16 E: 16 MB][all_sum: 32 KB][pos_sum: 32 KB]
    unsigned short* Ebf = (unsigned short*)d_ws;
    const size_t embBytes = (size_t)NROWS * DIM * sizeof(unsigned short);
    float* all_sum = (float*)((char*)d_ws + embBytes);
    float* pos_sum = all_sum + NROWS;

    convert_kernel<<<(NROWS * DIM) / (4 * 256), 256, 0, stream>>>(emb, Ebf, all_sum);

    gemm_fused_kernel<<<NBLK, 512, 0, stream>>>(Ebf, labels, all_sum, pos_sum);

    finalize_kernel<<<1, 1024, 0, stream>>>(all_sum, pos_sum, labels, out);
}